// Round 2
// baseline (586.712 us; speedup 1.0000x reference)
//
#include <hip/hip_runtime.h>
#include <math.h>

#define NB 32
#define NQ 16
#define NP 196
#define OUTW 3840

// ---------- resize weights (jax.image.resize, triangle kernel, antialias=True) ----------
template<int N>
__device__ __forceinline__ int calc_w(int i, float* w, int& lo) {
  constexpr float inv = (float)N / 14.0f;          // 4, 2, 0.5 — exact
  constexpr float ks  = (inv > 1.0f) ? inv : 1.0f; // kernel_scale = max(inv_scale, 1)
  constexpr float rks = 1.0f / ks;
  float sf = ((float)i + 0.5f) * inv - 0.5f;
  int l = (int)ceilf(sf - ks);
  int h = (int)floorf(sf + ks);
  if (l < 0) l = 0;
  if (h > N - 1) h = N - 1;
  int n = h - l + 1;
  float sum = 0.f;
  for (int k = 0; k < n; ++k) {
    float t = 1.0f - fabsf((float)(l + k) - sf) * rks;
    t = t > 0.f ? t : 0.f;
    w[k] = t; sum += t;
  }
  float r = 1.0f / sum;
  for (int k = 0; k < n; ++k) w[k] *= r;
  lo = l;
  return n;
}

// ---------- K0: bilinear resize NxN -> 14x14, one block per (sample, channel) plane ----------
template<int N>
__global__ void k_resize(const float* __restrict__ x, float* __restrict__ xr) {
  __shared__ float plane[N * N];
  const int bid = blockIdx.x;        // s*cm + c  (linear)
  const int t = threadIdx.x;
  const float* src = x + (size_t)bid * (N * N);
  for (int idx = t; idx < N * N; idx += 256) plane[idx] = src[idx];
  __syncthreads();
  if (t < NP) {
    int oy = t / 14, ox = t % 14;
    float wy[8], wx[8];
    int ly, lx;
    int ny = calc_w<N>(oy, wy, ly);
    int nx = calc_w<N>(ox, wx, lx);
    float acc = 0.f;
    for (int a = 0; a < ny; ++a) {
      const float* row = plane + (ly + a) * N + lx;
      float h = 0.f;
      for (int b = 0; b < nx; ++b) h = fmaf(wx[b], row[b], h);
      acc = fmaf(wy[a], h, acc);
    }
    xr[(size_t)bid * NP + t] = acc;
  }
}

// ---------- K1: per (sample, 64-channel chunk): partial {sum, sumsq, Y=W*Xr} ----------
#define CC 64
__global__ void k_stats(const float* __restrict__ xr, const float* __restrict__ W,
                        float* __restrict__ part, int cm, int nch) {
  __shared__ float tile[CC * NP];   // 49 KB
  __shared__ float wl[NQ * CC];     // 4 KB
  const int t = threadIdx.x;
  const int s = blockIdx.x / nch;
  const int ch = blockIdx.x % nch;
  const int c0 = ch * CC;
  const float* src = xr + ((size_t)s * cm + c0) * NP;
  for (int idx = t; idx < CC * NP; idx += 256) tile[idx] = src[idx];
  for (int idx = t; idx < NQ * CC; idx += 256) {
    int q = idx / CC, cc = idx % CC;
    wl[idx] = W[q * cm + c0 + cc];
  }
  __syncthreads();
  if (t < NP) {
    float s1 = 0.f, s2 = 0.f, y[NQ];
#pragma unroll
    for (int q = 0; q < NQ; ++q) y[q] = 0.f;
    for (int cc = 0; cc < CC; ++cc) {
      float v = tile[cc * NP + t];
      s1 += v; s2 = fmaf(v, v, s2);
#pragma unroll
      for (int q = 0; q < NQ; ++q) y[q] = fmaf(wl[q * CC + cc], v, y[q]);
    }
    float* pb = part + ((size_t)(s * nch + ch) * 18) * NP + t;
    pb[0] = s1;
    pb[NP] = s2;
#pragma unroll
    for (int q = 0; q < NQ; ++q) pb[(size_t)(2 + q) * NP] = y[q];
  }
}

// ---------- K2: per sample: combine partials, mu/rsd, H=sigmoid, G=HH^T, invert G ----------
__global__ void k_head(const float* __restrict__ part, const float* __restrict__ W,
                       float* __restrict__ murs, float* __restrict__ hws,
                       float* __restrict__ mws, int cm, int nch) {
  __shared__ float red[256];
  __shared__ float wsum[NQ];
  __shared__ float Hl[NQ * NP];     // 12.5 KB
  __shared__ float aug[16 * 33];
  const int t = threadIdx.x;
  const int s = blockIdx.x;

  // wsum[q] = sum_c W[q][c]
  {
    int q = t >> 4, l = t & 15;
    float p = 0.f;
    for (int c = l; c < cm; c += 16) p += W[q * cm + c];
    red[t] = p;
  }
  __syncthreads();
  if (t < NQ) {
    float v = 0.f;
    for (int k = 0; k < 16; ++k) v += red[t * 16 + k];
    wsum[t] = v;
  }
  __syncthreads();

  // combine partials, compute mu/rsd and H
  if (t < NP) {
    float s1 = 0.f, s2 = 0.f, y[NQ];
#pragma unroll
    for (int q = 0; q < NQ; ++q) y[q] = 0.f;
    for (int ch = 0; ch < nch; ++ch) {
      const float* pb = part + ((size_t)(s * nch + ch) * 18) * NP + t;
      s1 += pb[0];
      s2 += pb[NP];
#pragma unroll
      for (int q = 0; q < NQ; ++q) y[q] += pb[(size_t)(2 + q) * NP];
    }
    float mu = s1 / (float)cm;
    float var = (s2 - s1 * mu) / (float)(cm - 1);
    float rsd = (var > 0.f) ? (1.0f / sqrtf(var)) : 0.f;
    murs[((size_t)s * 2) * NP + t] = mu;
    murs[((size_t)s * 2 + 1) * NP + t] = rsd;
#pragma unroll
    for (int q = 0; q < NQ; ++q) {
      float arg = (y[q] - wsum[q] * mu) * rsd;
      Hl[q * NP + t] = 1.0f / (1.0f + expf(-arg));
    }
  }
  __syncthreads();

  // write H to global for K3
  for (int idx = t; idx < NQ * NP; idx += 256)
    hws[(size_t)s * NQ * NP + idx] = Hl[idx];

  // G = H H^T  (16x16, thread = (q1,q2))
  {
    int q1 = t >> 4, q2 = t & 15;
    float g = 0.f;
    for (int p = 0; p < NP; ++p) g = fmaf(Hl[q1 * NP + p], Hl[q2 * NP + p], g);
    aug[q1 * 33 + q2] = g;
    aug[q1 * 33 + 16 + q2] = (q1 == q2) ? 1.0f : 0.f;
  }
  __syncthreads();

  // Gauss-Jordan (G is SPD, no pivoting)
  for (int k = 0; k < 16; ++k) {
    float rpv = 1.0f / aug[k * 33 + k];
    __syncthreads();
    if (t < 32) aug[k * 33 + t] *= rpv;
    __syncthreads();
    int i = t >> 4, j = t & 15;
    float f = aug[i * 33 + k];
    __syncthreads();
    if (i != k) {
      aug[i * 33 + j]      -= f * aug[k * 33 + j];
      aug[i * 33 + 16 + j] -= f * aug[k * 33 + 16 + j];
    }
    __syncthreads();
  }
  {
    int i = t >> 4, j = t & 15;
    mws[(size_t)s * 256 + t] = aug[i * 33 + 16 + j];
  }
}

// ---------- K3: per (sample, 32-channel chunk): C = Xn H^T, b = C M, out = var(b) ----------
#define CC3 32
__global__ void k_var(const float* __restrict__ xr, const float* __restrict__ murs,
                      const float* __restrict__ hws, const float* __restrict__ mws,
                      float* __restrict__ out, int cm, int ooff) {
  __shared__ float tile[CC3 * NP];  // 24.5 KB
  __shared__ float Hl[NQ * NP];     // 12.5 KB
  __shared__ float mu[NP], rsd[NP];
  __shared__ float Ml[256];
  __shared__ float cmat[CC3 * NQ];
  const int t = threadIdx.x;        // 512 threads
  const int nch = cm / CC3;
  const int s = blockIdx.x / nch;
  const int ch = blockIdx.x % nch;
  const int c0 = ch * CC3;
  const float* src = xr + ((size_t)s * cm + c0) * NP;
  for (int idx = t; idx < CC3 * NP; idx += 512) tile[idx] = src[idx];
  for (int idx = t; idx < NQ * NP; idx += 512) Hl[idx] = hws[(size_t)s * NQ * NP + idx];
  for (int idx = t; idx < NP; idx += 512) {
    mu[idx]  = murs[((size_t)s * 2) * NP + idx];
    rsd[idx] = murs[((size_t)s * 2 + 1) * NP + idx];
  }
  if (t < 256) Ml[t] = mws[(size_t)s * 256 + t];
  __syncthreads();
  for (int idx = t; idx < CC3 * NP; idx += 512) {
    int p = idx % NP;
    tile[idx] = (tile[idx] - mu[p]) * rsd[p];
  }
  __syncthreads();
  {
    int cc = t >> 4, q = t & 15;
    const float* tr = tile + cc * NP;
    const float* hr = Hl + q * NP;
    float acc = 0.f;
    for (int p = 0; p < NP; ++p) acc = fmaf(tr[p], hr[p], acc);
    cmat[cc * NQ + q] = acc;
  }
  __syncthreads();
  if (t < CC3) {
    float b[NQ];
    float mean = 0.f;
#pragma unroll
    for (int j = 0; j < NQ; ++j) {
      float v = 0.f;
#pragma unroll
      for (int q = 0; q < NQ; ++q) v = fmaf(cmat[t * NQ + q], Ml[q * 16 + j], v);
      b[j] = v; mean += v;
    }
    mean *= (1.0f / 16.0f);
    float var = 0.f;
#pragma unroll
    for (int j = 0; j < NQ; ++j) { float d = b[j] - mean; var = fmaf(d, d, var); }
    var *= (1.0f / 15.0f);
    out[(size_t)s * OUTW + ooff + c0 + t] = var;
  }
}

extern "C" void kernel_launch(void* const* d_in, const int* in_sizes, int n_in,
                              void* d_out, int out_size, void* d_ws, size_t ws_size,
                              hipStream_t stream) {
  const float* x0 = (const float*)d_in[0];
  const float* W0 = (const float*)d_in[1];
  const float* x1 = (const float*)d_in[2];
  const float* W1 = (const float*)d_in[3];
  const float* x2 = (const float*)d_in[4];
  const float* W2 = (const float*)d_in[5];
  const float* x3 = (const float*)d_in[6];
  const float* W3 = (const float*)d_in[7];
  float* out = (float*)d_out;
  float* ws = (float*)d_ws;

  // workspace layout (floats)
  float* xr0 = ws;                                   // 32*256*196
  float* xr1 = xr0 + (size_t)NB * 256 * NP;          // 32*512*196
  float* xr3 = xr1 + (size_t)NB * 512 * NP;          // 32*2048*196
  float* part0 = xr3 + (size_t)NB * 2048 * NP;
  size_t pl0 = (size_t)NB * 4  * 18 * NP;
  size_t pl1 = (size_t)NB * 8  * 18 * NP;
  size_t pl2 = (size_t)NB * 16 * 18 * NP;
  size_t pl3 = (size_t)NB * 32 * 18 * NP;
  float* part1 = part0 + pl0;
  float* part2 = part1 + pl1;
  float* part3 = part2 + pl2;
  float* murs = part3 + pl3;                         // [4][32][2][196]
  float* hws  = murs + (size_t)4 * NB * 2 * NP;      // [4][32][16][196]
  float* mws  = hws  + (size_t)4 * NB * NQ * NP;     // [4][32][256]

  float* murs_m[4], *hws_m[4], *mws_m[4];
  for (int m = 0; m < 4; ++m) {
    murs_m[m] = murs + (size_t)m * NB * 2 * NP;
    hws_m[m]  = hws  + (size_t)m * NB * NQ * NP;
    mws_m[m]  = mws  + (size_t)m * NB * 256;
  }

  // K0: resize (member 2 is identity -> use x2 directly)
  k_resize<56><<<NB * 256, 256, 0, stream>>>(x0, xr0);
  k_resize<28><<<NB * 512, 256, 0, stream>>>(x1, xr1);
  k_resize<7><<<NB * 2048, 256, 0, stream>>>(x3, xr3);

  // K1: stats + Y partials
  k_stats<<<NB * 4,  256, 0, stream>>>(xr0, W0, part0, 256, 4);
  k_stats<<<NB * 8,  256, 0, stream>>>(xr1, W1, part1, 512, 8);
  k_stats<<<NB * 16, 256, 0, stream>>>(x2,  W2, part2, 1024, 16);
  k_stats<<<NB * 32, 256, 0, stream>>>(xr3, W3, part3, 2048, 32);

  // K2: head (mu/rsd, H, G^-1)
  k_head<<<NB, 256, 0, stream>>>(part0, W0, murs_m[0], hws_m[0], mws_m[0], 256, 4);
  k_head<<<NB, 256, 0, stream>>>(part1, W1, murs_m[1], hws_m[1], mws_m[1], 512, 8);
  k_head<<<NB, 256, 0, stream>>>(part2, W2, murs_m[2], hws_m[2], mws_m[2], 1024, 16);
  k_head<<<NB, 256, 0, stream>>>(part3, W3, murs_m[3], hws_m[3], mws_m[3], 2048, 32);

  // K3: C GEMM + variance -> out
  k_var<<<NB * (256 / CC3),  512, 0, stream>>>(xr0, murs_m[0], hws_m[0], mws_m[0], out, 256, 0);
  k_var<<<NB * (512 / CC3),  512, 0, stream>>>(xr1, murs_m[1], hws_m[1], mws_m[1], out, 512, 256);
  k_var<<<NB * (1024 / CC3), 512, 0, stream>>>(x2,  murs_m[2], hws_m[2], mws_m[2], out, 1024, 768);
  k_var<<<NB * (2048 / CC3), 512, 0, stream>>>(xr3, murs_m[3], hws_m[3], mws_m[3], out, 2048, 1792);
  (void)in_sizes; (void)n_in; (void)out_size; (void)ws_size;
}

// Round 3
// 332.675 us; speedup vs baseline: 1.7636x; 1.7636x over previous
//
#include <hip/hip_runtime.h>
#include <math.h>

#define NB 32
#define NQ 16
#define NP 196
#define OUTW 3840

// ---------- resize weights (jax.image.resize, triangle kernel, antialias=True) ----------
template<int N>
__device__ __forceinline__ int calc_w(int i, float* w, int& lo) {
  constexpr float inv = (float)N / 14.0f;          // 4, 2, 0.5 — exact
  constexpr float ks  = (inv > 1.0f) ? inv : 1.0f; // kernel_scale = max(inv_scale, 1)
  constexpr float rks = 1.0f / ks;
  float sf = ((float)i + 0.5f) * inv - 0.5f;
  int l = (int)ceilf(sf - ks);
  int h = (int)floorf(sf + ks);
  if (l < 0) l = 0;
  if (h > N - 1) h = N - 1;
  int n = h - l + 1;
  float sum = 0.f;
  for (int k = 0; k < n; ++k) {
    float t = 1.0f - fabsf((float)(l + k) - sf) * rks;
    t = t > 0.f ? t : 0.f;
    w[k] = t; sum += t;
  }
  float r = 1.0f / sum;
  for (int k = 0; k < n; ++k) w[k] *= r;
  lo = l;
  return n;
}

// ---------- K0: separable resize, PPB planes per block ----------
template<int N, int PPB>
__global__ void k_resize(const float* __restrict__ x, float* __restrict__ xr) {
  constexpr int TS = 15;   // tmp stride (odd-ish -> spreads banks)
  __shared__ __align__(16) float plane[PPB * N * N];
  __shared__ float tmp[PPB * N * TS];
  __shared__ float wya[14 * 8], wxa[14 * 8];
  __shared__ int lya[14], lxa[14], nya[14], nxa[14];
  const int t = threadIdx.x;
  const int bid = blockIdx.x;

  // coalesced float4 load of PPB contiguous planes
  constexpr int NV = PPB * N * N / 4;
  const float4* src = (const float4*)(x + (size_t)bid * PPB * N * N);
  float4* pl4 = (float4*)plane;
  for (int i = t; i < NV; i += 256) pl4[i] = src[i];

  // weights once per block (two different waves)
  if (t < 14)                  nya[t] = calc_w<N>(t, &wya[t * 8], lya[t]);
  else if (t >= 64 && t < 78) { int i = t - 64; nxa[i] = calc_w<N>(i, &wxa[i * 8], lxa[i]); }
  __syncthreads();

  // pass 1: horizontal  [N][N] -> [N][14]
  for (int i = t; i < PPB * N * 14; i += 256) {
    int pl = i / (N * 14), rem = i - pl * (N * 14);
    int r = rem / 14, ox = rem - r * 14;
    const float* prow = plane + pl * N * N + r * N + lxa[ox];
    const float* w = &wxa[ox * 8];
    int n = nxa[ox];
    float acc = 0.f;
    for (int b = 0; b < n; ++b) acc = fmaf(w[b], prow[b], acc);
    tmp[pl * N * TS + r * TS + ox] = acc;
  }
  __syncthreads();

  // pass 2: vertical  [N][14] -> [14][14]
  for (int i = t; i < PPB * NP; i += 256) {
    int pl = i / NP, rem = i - pl * NP;
    int oy = rem / 14, ox = rem - oy * 14;
    const float* tcol = tmp + pl * N * TS + lya[oy] * TS + ox;
    const float* w = &wya[oy * 8];
    int n = nya[oy];
    float acc = 0.f;
    for (int a = 0; a < n; ++a) acc = fmaf(w[a], tcol[a * TS], acc);
    xr[(size_t)bid * PPB * NP + i] = acc;
  }
}

// ---------- K1: per (sample, 64-ch chunk): partial {sum, sumsq, Y=W*Xr}, no LDS ----------
#define CC 64
__global__ void k_stats(const float* __restrict__ xr, const float* __restrict__ W,
                        float* __restrict__ part, int cm, int nch) {
  const int t = threadIdx.x;
  if (t >= NP) return;
  const int s = blockIdx.x / nch;
  const int ch = blockIdx.x % nch;
  const int c0 = ch * CC;
  const float* src = xr + ((size_t)s * cm + c0) * NP + t;   // lane-coalesced
  const float* wp = W + c0;                                  // wave-uniform -> s_load
  float s1 = 0.f, s2 = 0.f, y[NQ];
#pragma unroll
  for (int q = 0; q < NQ; ++q) y[q] = 0.f;
  for (int cc = 0; cc < CC; ++cc) {
    float v = src[(size_t)cc * NP];
    s1 += v; s2 = fmaf(v, v, s2);
#pragma unroll
    for (int q = 0; q < NQ; ++q) y[q] = fmaf(wp[q * cm + cc], v, y[q]);
  }
  float* pb = part + ((size_t)(s * nch + ch) * 18) * NP + t;
  pb[0] = s1;
  pb[NP] = s2;
#pragma unroll
  for (int q = 0; q < NQ; ++q) pb[(size_t)(2 + q) * NP] = y[q];
}

// ---------- K2: combine partials, H, G^-1, emit HM = rsd*(H^T M) and e ----------
struct HeadArgs {
  const float* part[4];
  const float* W[4];
  float* hm[4];
  int cm[4];
  int nch[4];
};

__global__ void k_head(HeadArgs A) {
  const int m = blockIdx.y, s = blockIdx.x, t = threadIdx.x;
  const int cm = A.cm[m], nch = A.nch[m];
  const float* W = A.W[m];
  const float* part = A.part[m];
  float* hm = A.hm[m];

  __shared__ float red[256];
  __shared__ float wsum[NQ];
  __shared__ float Hl[NQ * NP];
  __shared__ float HMl[NQ * NP];
  __shared__ float mul[NP], rsdl[NP];
  __shared__ float aug[16 * 33];
  __shared__ float Ml[256];

  // wsum[q] = sum_c W[q][c]
  { int q = t >> 4, l = t & 15;
    float p = 0.f;
    for (int c = l; c < cm; c += 16) p += W[q * cm + c];
    red[t] = p; }
  __syncthreads();
  if (t < NQ) { float v = 0.f; for (int k = 0; k < 16; ++k) v += red[t * 16 + k]; wsum[t] = v; }
  __syncthreads();

  // combine partials -> mu, rsd, H
  if (t < NP) {
    float s1 = 0.f, s2 = 0.f, y[NQ];
#pragma unroll
    for (int q = 0; q < NQ; ++q) y[q] = 0.f;
    for (int ch = 0; ch < nch; ++ch) {
      const float* pb = part + ((size_t)(s * nch + ch) * 18) * NP + t;
      s1 += pb[0];
      s2 += pb[NP];
#pragma unroll
      for (int q = 0; q < NQ; ++q) y[q] += pb[(size_t)(2 + q) * NP];
    }
    float mu = s1 / (float)cm;
    float var = (s2 - s1 * mu) / (float)(cm - 1);
    float rsd = (var > 0.f) ? (1.0f / sqrtf(var)) : 0.f;
    mul[t] = mu; rsdl[t] = rsd;
#pragma unroll
    for (int q = 0; q < NQ; ++q) {
      float arg = (y[q] - wsum[q] * mu) * rsd;
      Hl[q * NP + t] = 1.0f / (1.0f + expf(-arg));
    }
  }
  __syncthreads();

  // G = H H^T
  { int q1 = t >> 4, q2 = t & 15;
    float g = 0.f;
    for (int p = 0; p < NP; ++p) g = fmaf(Hl[q1 * NP + p], Hl[q2 * NP + p], g);
    aug[q1 * 33 + q2] = g;
    aug[q1 * 33 + 16 + q2] = (q1 == q2) ? 1.0f : 0.f; }
  __syncthreads();

  // Gauss-Jordan (SPD, no pivoting)
  for (int k = 0; k < 16; ++k) {
    float rpv = 1.0f / aug[k * 33 + k];
    __syncthreads();
    if (t < 32) aug[k * 33 + t] *= rpv;
    __syncthreads();
    int i = t >> 4, j = t & 15;
    float f = aug[i * 33 + k];
    __syncthreads();
    if (i != k) {
      aug[i * 33 + j]      -= f * aug[k * 33 + j];
      aug[i * 33 + 16 + j] -= f * aug[k * 33 + 16 + j];
    }
    __syncthreads();
  }
  { int i = t >> 4, j = t & 15; Ml[t] = aug[i * 33 + 16 + j]; }
  __syncthreads();

  // HM[j][p] = rsd[p] * sum_q M[j][q] H[q][p]
  if (t < NP) {
    float r_ = rsdl[t];
#pragma unroll
    for (int j = 0; j < NQ; ++j) {
      float acc = 0.f;
#pragma unroll
      for (int q = 0; q < NQ; ++q) acc = fmaf(Ml[j * 16 + q], Hl[q * NP + t], acc);
      HMl[j * NP + t] = acc * r_;
    }
  }
  __syncthreads();

  float* dst = hm + (size_t)s * (NQ * NP + NQ);
  for (int i = t; i < NQ * NP; i += 256) dst[i] = HMl[i];

  // e[j] = sum_p mu[p] * HM[j][p]
  { int j = t >> 4, l = t & 15;
    float p = 0.f;
    for (int pp = l; pp < NP; pp += 16) p = fmaf(mul[pp], HMl[j * NP + pp], p);
    red[t] = p; }
  __syncthreads();
  if (t < NQ) { float v = 0.f; for (int k = 0; k < 16; ++k) v += red[t * 16 + k]; dst[NQ * NP + t] = v; }
}

// ---------- K3: b[cc][j] = dot(x_row, HM[j]) - e[j];  out = var_j(b) ----------
#define CC3 32
__global__ __launch_bounds__(512) void k_var(const float* __restrict__ xr,
                                             const float* __restrict__ hm,
                                             float* __restrict__ out, int cm, int ooff) {
  __shared__ __align__(16) float tile[CC3 * NP];   // 24.5 KB
  __shared__ __align__(16) float hml[NQ * NP];     // 12.25 KB
  __shared__ float el[NQ];
  const int t = threadIdx.x;
  const int nch = cm / CC3;
  const int s = blockIdx.x / nch;
  const int ch = blockIdx.x % nch;

  const float4* src = (const float4*)(xr + ((size_t)s * cm + ch * CC3) * NP);
  float4* t4 = (float4*)tile;
  for (int i = t; i < CC3 * NP / 4; i += 512) t4[i] = src[i];
  const float4* hsrc = (const float4*)(hm + (size_t)s * (NQ * NP + NQ));
  float4* h4 = (float4*)hml;
  for (int i = t; i < NQ * NP / 4; i += 512) h4[i] = hsrc[i];
  if (t < NQ) el[t] = hm[(size_t)s * (NQ * NP + NQ) + NQ * NP + t];
  __syncthreads();

  const int cc = t >> 4, j = t & 15;
  const float4* tr = (const float4*)(tile + cc * NP);
  const float4* hr = (const float4*)(hml + j * NP);
  float acc = 0.f;
#pragma unroll 7
  for (int p4 = 0; p4 < NP / 4; ++p4) {
    float4 a = tr[p4], b = hr[p4];
    acc = fmaf(a.x, b.x, acc);
    acc = fmaf(a.y, b.y, acc);
    acc = fmaf(a.z, b.z, acc);
    acc = fmaf(a.w, b.w, acc);
  }
  float bv = acc - el[j];

  // 16-lane variance reduce (two-pass for stability)
  float s1 = bv;
  s1 += __shfl_xor(s1, 1, 16);
  s1 += __shfl_xor(s1, 2, 16);
  s1 += __shfl_xor(s1, 4, 16);
  s1 += __shfl_xor(s1, 8, 16);
  float mean = s1 * (1.0f / 16.0f);
  float d = bv - mean;
  float s2 = d * d;
  s2 += __shfl_xor(s2, 1, 16);
  s2 += __shfl_xor(s2, 2, 16);
  s2 += __shfl_xor(s2, 4, 16);
  s2 += __shfl_xor(s2, 8, 16);
  if (j == 0) out[(size_t)s * OUTW + ooff + ch * CC3 + cc] = s2 * (1.0f / 15.0f);
}

extern "C" void kernel_launch(void* const* d_in, const int* in_sizes, int n_in,
                              void* d_out, int out_size, void* d_ws, size_t ws_size,
                              hipStream_t stream) {
  const float* x0 = (const float*)d_in[0];
  const float* W0 = (const float*)d_in[1];
  const float* x1 = (const float*)d_in[2];
  const float* W1 = (const float*)d_in[3];
  const float* x2 = (const float*)d_in[4];
  const float* W2 = (const float*)d_in[5];
  const float* x3 = (const float*)d_in[6];
  const float* W3 = (const float*)d_in[7];
  float* out = (float*)d_out;
  float* ws = (float*)d_ws;

  // workspace layout (floats)
  float* xr0 = ws;                                   // 32*256*196
  float* xr1 = xr0 + (size_t)NB * 256 * NP;          // 32*512*196
  float* xr3 = xr1 + (size_t)NB * 512 * NP;          // 32*2048*196
  float* part0 = xr3 + (size_t)NB * 2048 * NP;
  size_t pl0 = (size_t)NB * (256 / CC)  * 18 * NP;
  size_t pl1 = (size_t)NB * (512 / CC)  * 18 * NP;
  size_t pl2 = (size_t)NB * (1024 / CC) * 18 * NP;
  size_t pl3 = (size_t)NB * (2048 / CC) * 18 * NP;
  float* part1 = part0 + pl0;
  float* part2 = part1 + pl1;
  float* part3 = part2 + pl2;
  float* hm0 = part3 + pl3;                          // per member: 32*(16*196+16)
  size_t hl = (size_t)NB * (NQ * NP + NQ);
  float* hm1 = hm0 + hl;
  float* hm2 = hm1 + hl;
  float* hm3 = hm2 + hl;

  // K0: resize (member 2 is identity -> use x2 directly)
  k_resize<56, 1><<<NB * 256,      256, 0, stream>>>(x0, xr0);
  k_resize<28, 2><<<NB * 512 / 2,  256, 0, stream>>>(x1, xr1);
  k_resize<7,  8><<<NB * 2048 / 8, 256, 0, stream>>>(x3, xr3);

  // K1: stats + Y partials
  k_stats<<<NB * (256 / CC),  256, 0, stream>>>(xr0, W0, part0, 256, 256 / CC);
  k_stats<<<NB * (512 / CC),  256, 0, stream>>>(xr1, W1, part1, 512, 512 / CC);
  k_stats<<<NB * (1024 / CC), 256, 0, stream>>>(x2,  W2, part2, 1024, 1024 / CC);
  k_stats<<<NB * (2048 / CC), 256, 0, stream>>>(xr3, W3, part3, 2048, 2048 / CC);

  // K2: head (merged across members)
  HeadArgs A;
  A.part[0] = part0; A.part[1] = part1; A.part[2] = part2; A.part[3] = part3;
  A.W[0] = W0; A.W[1] = W1; A.W[2] = W2; A.W[3] = W3;
  A.hm[0] = hm0; A.hm[1] = hm1; A.hm[2] = hm2; A.hm[3] = hm3;
  A.cm[0] = 256; A.cm[1] = 512; A.cm[2] = 1024; A.cm[3] = 2048;
  A.nch[0] = 256 / CC; A.nch[1] = 512 / CC; A.nch[2] = 1024 / CC; A.nch[3] = 2048 / CC;
  k_head<<<dim3(NB, 4), 256, 0, stream>>>(A);

  // K3: dot vs HM + variance -> out
  k_var<<<NB * (256 / CC3),  512, 0, stream>>>(xr0, hm0, out, 256, 0);
  k_var<<<NB * (512 / CC3),  512, 0, stream>>>(xr1, hm1, out, 512, 256);
  k_var<<<NB * (1024 / CC3), 512, 0, stream>>>(x2,  hm2, out, 1024, 768);
  k_var<<<NB * (2048 / CC3), 512, 0, stream>>>(xr3, hm3, out, 2048, 1792);
  (void)in_sizes; (void)n_in; (void)out_size; (void)ws_size;
}

// Round 4
// 254.707 us; speedup vs baseline: 2.3035x; 1.3061x over previous
//
#include <hip/hip_runtime.h>
#include <math.h>

#define NB 32
#define NQ 16
#define NP 196
#define OUTW 3840

// ---------- resize weights (jax.image.resize, triangle kernel, antialias=True) ----------
template<int N>
__device__ __forceinline__ int calc_w(int i, float* w, int& lo) {
  constexpr float inv = (float)N / 14.0f;          // 4, 2, 0.5 — exact
  constexpr float ks  = (inv > 1.0f) ? inv : 1.0f; // kernel_scale = max(inv_scale, 1)
  constexpr float rks = 1.0f / ks;
  float sf = ((float)i + 0.5f) * inv - 0.5f;
  int l = (int)ceilf(sf - ks);
  int h = (int)floorf(sf + ks);
  if (l < 0) l = 0;
  if (h > N - 1) h = N - 1;
  int n = h - l + 1;
  float sum = 0.f;
  for (int k = 0; k < n; ++k) {
    float t = 1.0f - fabsf((float)(l + k) - sf) * rks;
    t = t > 0.f ? t : 0.f;
    w[k] = t; sum += t;
  }
  float r = 1.0f / sum;
  for (int k = 0; k < n; ++k) w[k] *= r;
  lo = l;
  return n;
}

struct RSShared {
  float plane[3136];      // worst: N=56, PPB=1
  float tmp[840];         // worst: 56*15 / 2*28*15
  float xrt[784];         // worst: PPB=4 * 196
  float wya[14 * 8], wxa[14 * 8];
  int lya[14], lxa[14], nya[14], nxa[14];
};

struct RSArgs {
  const float* x[4];
  const float* W[4];
  float* xr[4];           // [2] unused
  float* part[4];
};

// ---------- fused resize + stats body (members 0,1,3) ----------
template<int N, int PPB, int CH_BLK>
__device__ __forceinline__ void rs_resize_body(
    const float* __restrict__ x, const float* __restrict__ W,
    float* __restrict__ xr, float* __restrict__ part,
    int s, int chunk, int cm, int nch, RSShared& sh) {
  const int t = threadIdx.x;
  if (t < 14)                  sh.nya[t] = calc_w<N>(t, &sh.wya[t * 8], sh.lya[t]);
  else if (t >= 64 && t < 78) { int i = t - 64; sh.nxa[i] = calc_w<N>(i, &sh.wxa[i * 8], sh.lxa[i]); }

  float s1 = 0.f, s2 = 0.f, y[NQ];
#pragma unroll
  for (int q = 0; q < NQ; ++q) y[q] = 0.f;
  const int c0 = chunk * CH_BLK;
  constexpr int NITER = CH_BLK / PPB;

  for (int ci = 0; ci < NITER; ++ci) {
    const int cbase = c0 + ci * PPB;
    // load PPB planes (float4, always 16B-aligned)
    const float4* src4 = (const float4*)(x + ((size_t)s * cm + cbase) * (N * N));
    float4* pl4 = (float4*)sh.plane;
    constexpr int NV = PPB * N * N / 4;
    for (int i = t; i < NV; i += 256) pl4[i] = src4[i];
    __syncthreads();
    // pass 1: horizontal [N][N] -> [N][14]
    constexpr int P1 = PPB * N * 14;
    for (int i = t; i < P1; i += 256) {
      int pl = i / (N * 14), rem = i - pl * (N * 14);
      int r = rem / 14, ox = rem - r * 14;
      const float* prow = sh.plane + pl * N * N + r * N + sh.lxa[ox];
      const float* w = &sh.wxa[ox * 8];
      int n = sh.nxa[ox];
      float acc = 0.f;
      for (int k = 0; k < n; ++k) acc = fmaf(w[k], prow[k], acc);
      sh.tmp[(pl * N + r) * 15 + ox] = acc;
    }
    __syncthreads();
    // pass 2: vertical [N][14] -> [14][14], write global xr + LDS xrt
    constexpr int P2 = PPB * NP;
    for (int i = t; i < P2; i += 256) {
      int pl = i / NP, rem = i - pl * NP;
      int oy = rem / 14, ox = rem - oy * 14;
      const float* tc = sh.tmp + (pl * N + sh.lya[oy]) * 15 + ox;
      const float* w = &sh.wya[oy * 8];
      int n = sh.nya[oy];
      float acc = 0.f;
      for (int k = 0; k < n; ++k) acc = fmaf(w[k], tc[k * 15], acc);
      xr[((size_t)s * cm + cbase + pl) * NP + rem] = acc;
      sh.xrt[pl * NP + rem] = acc;
    }
    __syncthreads();
    // stats accumulate (thread t owns pixel t)
    if (t < NP) {
#pragma unroll
      for (int pl = 0; pl < PPB; ++pl) {
        float v = sh.xrt[pl * NP + t];
        s1 += v; s2 = fmaf(v, v, s2);
        const float* wc = W + (cbase + pl);
#pragma unroll
        for (int q = 0; q < NQ; ++q) y[q] = fmaf(wc[q * cm], v, y[q]);
      }
    }
    // next-iter hazards covered by the loads→sync→pass1 ordering (see sync chain)
  }
  if (t < NP) {
    float* pb = part + (size_t)(s * nch + chunk) * 18 * NP + t;
    pb[0] = s1;
    pb[NP] = s2;
#pragma unroll
    for (int q = 0; q < NQ; ++q) pb[(size_t)(2 + q) * NP] = y[q];
  }
}

// ---------- stats-only body (member 2, identity resize) ----------
__device__ __forceinline__ void rs_stats_body(
    const float* __restrict__ x, const float* __restrict__ W,
    float* __restrict__ part, int s, int chunk, int cm, int nch) {
  const int t = threadIdx.x;
  if (t >= NP) return;
  float s1 = 0.f, s2 = 0.f, y[NQ];
#pragma unroll
  for (int q = 0; q < NQ; ++q) y[q] = 0.f;
  const int c0 = chunk * 64;
  const float* src = x + ((size_t)s * cm + c0) * NP + t;
  const float* wc = W + c0;
  for (int c = 0; c < 64; ++c) {
    float v = src[(size_t)c * NP];
    s1 += v; s2 = fmaf(v, v, s2);
#pragma unroll
    for (int q = 0; q < NQ; ++q) y[q] = fmaf(wc[q * cm + c], v, y[q]);
  }
  float* pb = part + (size_t)(s * nch + chunk) * 18 * NP + t;
  pb[0] = s1;
  pb[NP] = s2;
#pragma unroll
  for (int q = 0; q < NQ; ++q) pb[(size_t)(2 + q) * NP] = y[q];
}

// grid: m0 [0,512) m1 [512,1024) m2 [1024,1536) m3 [1536,2560)
__global__ __launch_bounds__(256) void k_rs(RSArgs A) {
  __shared__ RSShared sh;
  int b = blockIdx.x;
  if (b < 512) {
    rs_resize_body<56, 1, 16>(A.x[0], A.W[0], A.xr[0], A.part[0], b / 16, b % 16, 256, 16, sh);
  } else if (b < 1024) {
    b -= 512;
    rs_resize_body<28, 2, 32>(A.x[1], A.W[1], A.xr[1], A.part[1], b / 16, b % 16, 512, 16, sh);
  } else if (b < 1536) {
    b -= 1024;
    rs_stats_body(A.x[2], A.W[2], A.part[2], b / 16, b % 16, 1024, 16);
  } else {
    b -= 1536;
    rs_resize_body<7, 4, 64>(A.x[3], A.W[3], A.xr[3], A.part[3], b / 32, b % 32, 2048, 32, sh);
  }
}

// ---------- K2: combine partials, H, G^-1, emit HM = rsd*(H^T M) and e ----------
struct HeadArgs {
  const float* part[4];
  const float* W[4];
  float* hm[4];
  int cm[4];
  int nch[4];
};

__global__ void k_head(HeadArgs A) {
  const int m = blockIdx.y, s = blockIdx.x, t = threadIdx.x;
  const int cm = A.cm[m], nch = A.nch[m];
  const float* W = A.W[m];
  const float* part = A.part[m];
  float* hm = A.hm[m];

  __shared__ float red[256];
  __shared__ float wsum[NQ];
  __shared__ float Hl[NQ * NP];
  __shared__ float HMl[NQ * NP];
  __shared__ float mul[NP], rsdl[NP];
  __shared__ float aug[16 * 33];
  __shared__ float Ml[256];

  { int q = t >> 4, l = t & 15;
    float p = 0.f;
    for (int c = l; c < cm; c += 16) p += W[q * cm + c];
    red[t] = p; }
  __syncthreads();
  if (t < NQ) { float v = 0.f; for (int k = 0; k < 16; ++k) v += red[t * 16 + k]; wsum[t] = v; }
  __syncthreads();

  if (t < NP) {
    float s1 = 0.f, s2 = 0.f, y[NQ];
#pragma unroll
    for (int q = 0; q < NQ; ++q) y[q] = 0.f;
    for (int ch = 0; ch < nch; ++ch) {
      const float* pb = part + ((size_t)(s * nch + ch) * 18) * NP + t;
      s1 += pb[0];
      s2 += pb[NP];
#pragma unroll
      for (int q = 0; q < NQ; ++q) y[q] += pb[(size_t)(2 + q) * NP];
    }
    float mu = s1 / (float)cm;
    float var = (s2 - s1 * mu) / (float)(cm - 1);
    float rsd = (var > 0.f) ? (1.0f / sqrtf(var)) : 0.f;
    mul[t] = mu; rsdl[t] = rsd;
#pragma unroll
    for (int q = 0; q < NQ; ++q) {
      float arg = (y[q] - wsum[q] * mu) * rsd;
      Hl[q * NP + t] = 1.0f / (1.0f + expf(-arg));
    }
  }
  __syncthreads();

  { int q1 = t >> 4, q2 = t & 15;
    float g = 0.f;
    for (int p = 0; p < NP; ++p) g = fmaf(Hl[q1 * NP + p], Hl[q2 * NP + p], g);
    aug[q1 * 33 + q2] = g;
    aug[q1 * 33 + 16 + q2] = (q1 == q2) ? 1.0f : 0.f; }
  __syncthreads();

  for (int k = 0; k < 16; ++k) {
    float rpv = 1.0f / aug[k * 33 + k];
    __syncthreads();
    if (t < 32) aug[k * 33 + t] *= rpv;
    __syncthreads();
    int i = t >> 4, j = t & 15;
    float f = aug[i * 33 + k];
    __syncthreads();
    if (i != k) {
      aug[i * 33 + j]      -= f * aug[k * 33 + j];
      aug[i * 33 + 16 + j] -= f * aug[k * 33 + 16 + j];
    }
    __syncthreads();
  }
  { int i = t >> 4, j = t & 15; Ml[t] = aug[i * 33 + 16 + j]; }
  __syncthreads();

  if (t < NP) {
    float r_ = rsdl[t];
#pragma unroll
    for (int j = 0; j < NQ; ++j) {
      float acc = 0.f;
#pragma unroll
      for (int q = 0; q < NQ; ++q) acc = fmaf(Ml[j * 16 + q], Hl[q * NP + t], acc);
      HMl[j * NP + t] = acc * r_;
    }
  }
  __syncthreads();

  float* dst = hm + (size_t)s * (NQ * NP + NQ);
  for (int i = t; i < NQ * NP; i += 256) dst[i] = HMl[i];

  { int j = t >> 4, l = t & 15;
    float p = 0.f;
    for (int pp = l; pp < NP; pp += 16) p = fmaf(mul[pp], HMl[j * NP + pp], p);
    red[t] = p; }
  __syncthreads();
  if (t < NQ) { float v = 0.f; for (int k = 0; k < 16; ++k) v += red[t * 16 + k]; dst[NQ * NP + t] = v; }
}

// ---------- K3 merged: b[cc][j] = dot(x_row, HM[j]) - e[j];  out = var_j(b) ----------
#define CC3 32
struct VarArgs {
  const float* src[4];
  const float* hm[4];
  int cm[4];
  int ooff[4];
};

// grid: m0 [0,256) m1 [256,768) m2 [768,1792) m3 [1792,3840)
__global__ __launch_bounds__(512) void k_var(VarArgs A, float* __restrict__ out) {
  __shared__ __align__(16) float tile[CC3 * NP];   // 24.5 KB
  __shared__ __align__(16) float hml[NQ * NP];     // 12.25 KB
  __shared__ float el[NQ];
  int b = blockIdx.x;
  int m;
  if (b < 256)       { m = 0; }
  else if (b < 768)  { m = 1; b -= 256; }
  else if (b < 1792) { m = 2; b -= 768; }
  else               { m = 3; b -= 1792; }
  const int cm = A.cm[m];
  const int nch = cm / CC3;
  const int s = b / nch;
  const int ch = b % nch;
  const float* xr = A.src[m];
  const float* hm = A.hm[m];
  const int t = threadIdx.x;

  const float4* src = (const float4*)(xr + ((size_t)s * cm + ch * CC3) * NP);
  float4* t4 = (float4*)tile;
  for (int i = t; i < CC3 * NP / 4; i += 512) t4[i] = src[i];
  const float4* hsrc = (const float4*)(hm + (size_t)s * (NQ * NP + NQ));
  float4* h4 = (float4*)hml;
  for (int i = t; i < NQ * NP / 4; i += 512) h4[i] = hsrc[i];
  if (t < NQ) el[t] = hm[(size_t)s * (NQ * NP + NQ) + NQ * NP + t];
  __syncthreads();

  const int cc = t >> 4, j = t & 15;
  const float4* tr = (const float4*)(tile + cc * NP);
  const float4* hr = (const float4*)(hml + j * NP);
  float acc = 0.f;
#pragma unroll 7
  for (int p4 = 0; p4 < NP / 4; ++p4) {
    float4 a = tr[p4], b2 = hr[p4];
    acc = fmaf(a.x, b2.x, acc);
    acc = fmaf(a.y, b2.y, acc);
    acc = fmaf(a.z, b2.z, acc);
    acc = fmaf(a.w, b2.w, acc);
  }
  float bv = acc - el[j];

  float s1 = bv;
  s1 += __shfl_xor(s1, 1, 16);
  s1 += __shfl_xor(s1, 2, 16);
  s1 += __shfl_xor(s1, 4, 16);
  s1 += __shfl_xor(s1, 8, 16);
  float mean = s1 * (1.0f / 16.0f);
  float d = bv - mean;
  float s2 = d * d;
  s2 += __shfl_xor(s2, 1, 16);
  s2 += __shfl_xor(s2, 2, 16);
  s2 += __shfl_xor(s2, 4, 16);
  s2 += __shfl_xor(s2, 8, 16);
  if (j == 0) out[(size_t)s * OUTW + A.ooff[m] + ch * CC3 + cc] = s2 * (1.0f / 15.0f);
}

extern "C" void kernel_launch(void* const* d_in, const int* in_sizes, int n_in,
                              void* d_out, int out_size, void* d_ws, size_t ws_size,
                              hipStream_t stream) {
  const float* x0 = (const float*)d_in[0];
  const float* W0 = (const float*)d_in[1];
  const float* x1 = (const float*)d_in[2];
  const float* W1 = (const float*)d_in[3];
  const float* x2 = (const float*)d_in[4];
  const float* W2 = (const float*)d_in[5];
  const float* x3 = (const float*)d_in[6];
  const float* W3 = (const float*)d_in[7];
  float* out = (float*)d_out;
  float* ws = (float*)d_ws;

  // workspace layout (floats)
  float* xr0 = ws;                                   // 32*256*196
  float* xr1 = xr0 + (size_t)NB * 256 * NP;          // 32*512*196
  float* xr3 = xr1 + (size_t)NB * 512 * NP;          // 32*2048*196
  float* part0 = xr3 + (size_t)NB * 2048 * NP;
  size_t pl0 = (size_t)NB * 16 * 18 * NP;
  size_t pl1 = (size_t)NB * 16 * 18 * NP;
  size_t pl2 = (size_t)NB * 16 * 18 * NP;
  size_t pl3 = (size_t)NB * 32 * 18 * NP;
  float* part1 = part0 + pl0;
  float* part2 = part1 + pl1;
  float* part3 = part2 + pl2;
  float* hm0 = part3 + pl3;                          // per member: 32*(16*196+16)
  size_t hl = (size_t)NB * (NQ * NP + NQ);
  float* hm1 = hm0 + hl;
  float* hm2 = hm1 + hl;
  float* hm3 = hm2 + hl;

  // K1: fused resize+stats (single launch)
  RSArgs R;
  R.x[0] = x0; R.x[1] = x1; R.x[2] = x2; R.x[3] = x3;
  R.W[0] = W0; R.W[1] = W1; R.W[2] = W2; R.W[3] = W3;
  R.xr[0] = xr0; R.xr[1] = xr1; R.xr[2] = nullptr; R.xr[3] = xr3;
  R.part[0] = part0; R.part[1] = part1; R.part[2] = part2; R.part[3] = part3;
  k_rs<<<2560, 256, 0, stream>>>(R);

  // K2: head (merged across members)
  HeadArgs A;
  A.part[0] = part0; A.part[1] = part1; A.part[2] = part2; A.part[3] = part3;
  A.W[0] = W0; A.W[1] = W1; A.W[2] = W2; A.W[3] = W3;
  A.hm[0] = hm0; A.hm[1] = hm1; A.hm[2] = hm2; A.hm[3] = hm3;
  A.cm[0] = 256; A.cm[1] = 512; A.cm[2] = 1024; A.cm[3] = 2048;
  A.nch[0] = 16; A.nch[1] = 16; A.nch[2] = 16; A.nch[3] = 32;
  k_head<<<dim3(NB, 4), 256, 0, stream>>>(A);

  // K3: merged var
  VarArgs V;
  V.src[0] = xr0; V.src[1] = xr1; V.src[2] = x2; V.src[3] = xr3;
  V.hm[0] = hm0; V.hm[1] = hm1; V.hm[2] = hm2; V.hm[3] = hm3;
  V.cm[0] = 256; V.cm[1] = 512; V.cm[2] = 1024; V.cm[3] = 2048;
  V.ooff[0] = 0; V.ooff[1] = 256; V.ooff[2] = 768; V.ooff[3] = 1792;
  k_var<<<3840, 512, 0, stream>>>(V, out);
  (void)in_sizes; (void)n_in; (void)out_size; (void)ws_size;
}